// Round 1
// 168.386 us; speedup vs baseline: 1.0064x; 1.0064x over previous
//
#include <hip/hip_runtime.h>

#define T_TOK 2048
#define DM    512
#define DFF   512
#define NE    16

typedef __attribute__((ext_vector_type(8))) short bf16x8;
typedef __attribute__((ext_vector_type(4))) float f32x4;
typedef __attribute__((ext_vector_type(8))) unsigned short us8;

__device__ __forceinline__ unsigned short f2bf(float f) {
  unsigned int u = __float_as_uint(f);
  u += 0x7fffu + ((u >> 16) & 1u);   // round-to-nearest-even
  return (unsigned short)(u >> 16);
}

// async global->LDS DMA, 16 B per lane; lds base must be wave-uniform
__device__ __forceinline__ void dma16(const unsigned short* g, unsigned short* l) {
  __builtin_amdgcn_global_load_lds(
      (const __attribute__((address_space(1))) unsigned int*)g,
      (__attribute__((address_space(3))) unsigned int*)l, 16, 0, 0);
}

// XOR-swizzled LDS tile rows of 64 bf16 (128 B/row), chunk c of row r
// stored at slot c ^ (r & 7). DMA windows (1024 B) stay contiguous; readers
// get 2-way bank aliasing (free, m136).
#define LDSOFF(row, chunk) ((((row) << 7) + ((((chunk) ^ ((row) & 7))) << 4)))

#define MFMA(a,b,c) __builtin_amdgcn_mfma_f32_16x16x32_bf16((a),(b),(c),0,0,0)

// ---------------- prep: blocks 0..511 router, 512+ convert + zero out ------
__global__ __launch_bounds__(256) void prep_kernel(
    const float* __restrict__ x, const float* __restrict__ gw,
    const float* __restrict__ bias, int* __restrict__ counts,
    int* __restrict__ list, float* __restrict__ wgt,
    const float* __restrict__ sgu, const float* __restrict__ sdn,
    const float* __restrict__ egu, const float* __restrict__ edn,
    unsigned short* __restrict__ xb,   unsigned short* __restrict__ sgub,
    unsigned short* __restrict__ sdnb, unsigned short* __restrict__ egub,
    unsigned short* __restrict__ ednb, float* __restrict__ out)
{
  const int tid = threadIdx.x;
  if (blockIdx.x >= 512) {
    // zero out (2048*512 fp32 = 262144 float4) + convert fp32->bf16
    const int cb = blockIdx.x - 512;           // 0..7039
    const int ct = cb * 256 + tid;
    const int CT = 7040 * 256;
    const float4 z4 = {0.f, 0.f, 0.f, 0.f};
    for (int i = ct; i < 262144; i += CT) ((float4*)out)[i] = z4;
    // groups of 8: x 131072 | sgu 65536 | sdn 32768 | egu 1048576 | edn 524288
    int g = ct;
    const float* s; unsigned short* d; int l;
    if      (g <  131072) { s = x;   d = xb;   l = g;           }
    else if (g <  196608) { s = sgu; d = sgub; l = g -  131072; }
    else if (g <  229376) { s = sdn; d = sdnb; l = g -  196608; }
    else if (g < 1277952) { s = egu; d = egub; l = g -  229376; }
    else                  { s = edn; d = ednb; l = g - 1277952; }
    const float* p = s + (size_t)l * 8;
    float4 v0 = *(const float4*)p;
    float4 v1 = *(const float4*)(p + 4);
    us8 o;
    o[0]=f2bf(v0.x); o[1]=f2bf(v0.y); o[2]=f2bf(v0.z); o[3]=f2bf(v0.w);
    o[4]=f2bf(v1.x); o[5]=f2bf(v1.y); o[6]=f2bf(v1.z); o[7]=f2bf(v1.w);
    *(us8*)(d + (size_t)l * 8) = o;
    return;
  }

  // ---- router: one token per wave ----
  __shared__ float lg[4][16];
  __shared__ int bcnt[16], bbase[16];
  __shared__ int sel_s[4][3], pos_s[4][3];
  __shared__ float g_s[4][3];

  const int w = tid >> 6, lane = tid & 63;
  if (tid < 16) bcnt[tid] = 0;
  const int tok = blockIdx.x * 4 + w;
  const int e = lane & 15, part = lane >> 4;

  const float* xr = x + (size_t)tok * DM + part * 128;
  const float* wr = gw + (size_t)e * DM + part * 128;
  float acc = 0.f;
  #pragma unroll 8
  for (int i = 0; i < 128; i += 4) {
    float4 xv = *(const float4*)(xr + i);
    float4 wv = *(const float4*)(wr + i);
    acc += xv.x*wv.x + xv.y*wv.y + xv.z*wv.z + xv.w*wv.w;
  }
  acc += __shfl_xor(acc, 16);
  acc += __shfl_xor(acc, 32);
  if (lane < 16) lg[w][lane] = 1.f / (1.f + __expf(-acc));  // affinity
  __syncthreads();

  if (tid < 4) {
    float aff[16], sc[16];
    #pragma unroll
    for (int i = 0; i < 16; ++i) { aff[i] = lg[tid][i]; sc[i] = aff[i] + bias[i]; }
    int sel[3]; float sa[3]; float sum = 0.f;
    #pragma unroll
    for (int k = 0; k < 3; ++k) {
      float best = -1e30f; int bi = 0;
      for (int i = 0; i < 16; ++i) {
        bool used = false;
        for (int j = 0; j < k; ++j) used |= (sel[j] == i);
        if (!used && sc[i] > best) { best = sc[i]; bi = i; }
      }
      sel[k] = bi; sa[k] = aff[bi]; sum += aff[bi];
    }
    float inv = 1.f / (sum + 1e-9f);
    #pragma unroll
    for (int k = 0; k < 3; ++k) {
      int p = atomicAdd(&bcnt[sel[k]], 1);
      sel_s[tid][k] = sel[k]; pos_s[tid][k] = p; g_s[tid][k] = sa[k] * inv;
    }
  }
  __syncthreads();
  if (tid < 16) bbase[tid] = atomicAdd(&counts[tid], bcnt[tid]);
  __syncthreads();
  if (tid < 4) {
    #pragma unroll
    for (int k = 0; k < 3; ++k) {
      int E = sel_s[tid][k];
      int p = bbase[E] + pos_s[tid][k];
      list[E * T_TOK + p] = blockIdx.x * 4 + tid;
      wgt [E * T_TOK + p] = g_s[tid][k];
    }
  }
}

// ---------------- GEMM1: 128x64 tiles, double-buffered DMA staging ---------
// z=0 shared expert, z>=1 routed expert z-1. Fused silu(g)*u -> Hall (bf16).
// Wave grid 2x2: each wave owns 64 rows x 32 cols, acc[4][2] per matrix.
__global__ __launch_bounds__(256, 2) void gemm1_fused(
    const unsigned short* __restrict__ X, const unsigned short* __restrict__ Wsh,
    const unsigned short* __restrict__ Wex, unsigned short* __restrict__ Hall,
    const int* __restrict__ counts, const int* __restrict__ list)
{
  __shared__ unsigned short SA[2][128][64];   // 32 KB
  __shared__ unsigned short SG[2][64][64];    // 16 KB
  __shared__ unsigned short SU[2][64][64];    // 16 KB

  const int n0 = blockIdx.x * 64;           // H col block
  const int mt = blockIdx.y, z = blockIdx.z;
  int cnt, hb; const unsigned short* W;
  if (z == 0) { cnt = T_TOK; hb = 0; W = Wsh; }
  else {
    const int e = z - 1;
    cnt = counts[e];
    if (mt * 128 >= cnt) return;
    hb = T_TOK;
    for (int i = 0; i < e; ++i) hb += counts[i];
    W = Wex + (size_t)e * (2 * DFF * DM);
  }

  const int tid = threadIdx.x, w = tid >> 6, lane = tid & 63;
  // staging: wave w owns an 8-row stripe per 32-row window (4 windows for A)
  const int rsub = lane >> 3;                // 0..7 row within stripe
  const int cch  = (lane & 7) ^ rsub;        // src chunk (XOR swizzle)
  const unsigned short* ga[4];
  #pragma unroll
  for (int q = 0; q < 4; ++q) {
    int ra = mt * 128 + q * 32 + w * 8 + rsub;
    int rc = ra < cnt ? ra : cnt - 1;
    int tokr = (z == 0) ? rc : list[(z - 1) * T_TOK + rc];
    ga[q] = X + (size_t)tokr * DM + cch * 8;
  }
  const unsigned short *gg[2], *gu[2];
  #pragma unroll
  for (int q = 0; q < 2; ++q) {
    int rb = n0 + q * 32 + w * 8 + rsub;
    gg[q] = W + (size_t)rb * DM + cch * 8;
    gu[q] = W + (size_t)(DFF + rb) * DM + cch * 8;
  }
  unsigned short* lA[2][4]; unsigned short* lG[2][2]; unsigned short* lU[2][2];
  #pragma unroll
  for (int b = 0; b < 2; ++b) {
    #pragma unroll
    for (int q = 0; q < 4; ++q) lA[b][q] = &SA[b][q * 32 + w * 8][0];
    #pragma unroll
    for (int q = 0; q < 2; ++q) {
      lG[b][q] = &SG[b][q * 32 + w * 8][0];
      lU[b][q] = &SU[b][q * 32 + w * 8][0];
    }
  }

  const int wm = (w & 1) * 64;               // wave row base (0 / 64)
  const int wn = (w >> 1) * 32;              // wave col base (0 / 32)
  const int lr = lane & 15, qd = lane >> 4;
  const char* const sa = (const char*)SA;
  const char* const sg = (const char*)SG;
  const char* const su = (const char*)SU;

  const f32x4 z4 = {0.f, 0.f, 0.f, 0.f};
  f32x4 accg[4][2], accu[4][2];
  #pragma unroll
  for (int i = 0; i < 4; ++i)
    #pragma unroll
    for (int j = 0; j < 2; ++j) { accg[i][j] = z4; accu[i][j] = z4; }

  // prologue: stage tile 0 into buf 0
  #pragma unroll
  for (int q = 0; q < 4; ++q) dma16(ga[q], lA[0][q]);
  #pragma unroll
  for (int q = 0; q < 2; ++q) { dma16(gg[q], lG[0][q]); dma16(gu[q], lU[0][q]); }

  #pragma unroll
  for (int i = 0; i < DM / 64; ++i) {
    const int b = i & 1;
    __syncthreads();                         // buf b ready (drains all DMA)
    if (i + 1 < DM / 64) {
      const int k1 = (i + 1) * 64, nb = b ^ 1;
      #pragma unroll
      for (int q = 0; q < 4; ++q) dma16(ga[q] + k1, lA[nb][q]);
      #pragma unroll
      for (int q = 0; q < 2; ++q) {
        dma16(gg[q] + k1, lG[nb][q]);
        dma16(gu[q] + k1, lU[nb][q]);
      }
    }
    const int boA = b * 16384;               // A buffer byte offset (128*64*2)
    const int boB = b * 8192;                // G/U buffer byte offset
    #pragma unroll
    for (int ks = 0; ks < 2; ++ks) {
      const int ch = ks * 4 + qd;            // 16B chunk index in row
      bf16x8 a[4], g[2], u[2];
      #pragma unroll
      for (int sm = 0; sm < 4; ++sm)
        a[sm] = *(const bf16x8*)(sa + boA + LDSOFF(wm + sm * 16 + lr, ch));
      #pragma unroll
      for (int sn = 0; sn < 2; ++sn) {
        g[sn] = *(const bf16x8*)(sg + boB + LDSOFF(wn + sn * 16 + lr, ch));
        u[sn] = *(const bf16x8*)(su + boB + LDSOFF(wn + sn * 16 + lr, ch));
      }
      #pragma unroll
      for (int sm = 0; sm < 4; ++sm)
        #pragma unroll
        for (int sn = 0; sn < 2; ++sn) {
          accg[sm][sn] = MFMA(a[sm], g[sn], accg[sm][sn]);
          accu[sm][sn] = MFMA(a[sm], u[sn], accu[sm][sn]);
        }
    }
  }

  #pragma unroll
  for (int sm = 0; sm < 4; ++sm)
    #pragma unroll
    for (int sn = 0; sn < 2; ++sn) {
      const int col = n0 + wn + sn * 16 + lr;
      #pragma unroll
      for (int r = 0; r < 4; ++r) {
        const int ent = mt * 128 + wm + sm * 16 + qd * 4 + r;
        if (ent < cnt) {
          float g = accg[sm][sn][r];
          float u = accu[sm][sn][r];
          float h = (g / (1.f + __expf(-g))) * u;   // silu(g)*u
          Hall[(size_t)(hb + ent) * DFF + col] = f2bf(h);
        }
      }
    }
}

// ---------------- GEMM2: 128x64 tiles, double-buffered DMA staging ---------
__global__ __launch_bounds__(256, 3) void gemm2_fused(
    const unsigned short* __restrict__ Hall, const unsigned short* __restrict__ Wsh,
    const unsigned short* __restrict__ Wex, float* __restrict__ out,
    const int* __restrict__ counts, const int* __restrict__ list,
    const float* __restrict__ wgt)
{
  __shared__ unsigned short SA[2][128][64];   // 32 KB
  __shared__ unsigned short SB[2][64][64];    // 16 KB

  const int n0 = blockIdx.x * 64;           // out col block
  const int mt = blockIdx.y, z = blockIdx.z;
  int cnt, hb; const unsigned short* W;
  if (z == 0) { cnt = T_TOK; hb = 0; W = Wsh; }
  else {
    const int e = z - 1;
    cnt = counts[e];
    if (mt * 128 >= cnt) return;
    hb = T_TOK;
    for (int i = 0; i < e; ++i) hb += counts[i];
    W = Wex + (size_t)e * (DM * DFF);
  }

  const int tid = threadIdx.x, w = tid >> 6, lane = tid & 63;
  const int rsub = lane >> 3;
  const int cch  = (lane & 7) ^ rsub;
  const unsigned short* ga[4];
  #pragma unroll
  for (int q = 0; q < 4; ++q) {
    int ra = mt * 128 + q * 32 + w * 8 + rsub;
    int rc = ra < cnt ? ra : cnt - 1;
    ga[q] = Hall + (size_t)(hb + rc) * DFF + cch * 8;
  }
  const unsigned short* gb[2];
  #pragma unroll
  for (int q = 0; q < 2; ++q)
    gb[q] = W + (size_t)(n0 + q * 32 + w * 8 + rsub) * DFF + cch * 8;
  unsigned short* lA[2][4]; unsigned short* lB[2][2];
  #pragma unroll
  for (int b = 0; b < 2; ++b) {
    #pragma unroll
    for (int q = 0; q < 4; ++q) lA[b][q] = &SA[b][q * 32 + w * 8][0];
    #pragma unroll
    for (int q = 0; q < 2; ++q) lB[b][q] = &SB[b][q * 32 + w * 8][0];
  }

  const int wm = (w & 1) * 64;
  const int wn = (w >> 1) * 32;
  const int lr = lane & 15, qd = lane >> 4;
  const char* const sa = (const char*)SA;
  const char* const sb = (const char*)SB;

  const f32x4 z4 = {0.f, 0.f, 0.f, 0.f};
  f32x4 acc[4][2];
  #pragma unroll
  for (int i = 0; i < 4; ++i)
    #pragma unroll
    for (int j = 0; j < 2; ++j) acc[i][j] = z4;

  #pragma unroll
  for (int q = 0; q < 4; ++q) dma16(ga[q], lA[0][q]);
  #pragma unroll
  for (int q = 0; q < 2; ++q) dma16(gb[q], lB[0][q]);

  #pragma unroll
  for (int i = 0; i < DFF / 64; ++i) {
    const int b = i & 1;
    __syncthreads();
    if (i + 1 < DFF / 64) {
      const int k1 = (i + 1) * 64, nb = b ^ 1;
      #pragma unroll
      for (int q = 0; q < 4; ++q) dma16(ga[q] + k1, lA[nb][q]);
      #pragma unroll
      for (int q = 0; q < 2; ++q) dma16(gb[q] + k1, lB[nb][q]);
    }
    const int boA = b * 16384;
    const int boB = b * 8192;
    #pragma unroll
    for (int ks = 0; ks < 2; ++ks) {
      const int ch = ks * 4 + qd;
      bf16x8 a[4], bb[2];
      #pragma unroll
      for (int sm = 0; sm < 4; ++sm)
        a[sm] = *(const bf16x8*)(sa + boA + LDSOFF(wm + sm * 16 + lr, ch));
      #pragma unroll
      for (int sn = 0; sn < 2; ++sn)
        bb[sn] = *(const bf16x8*)(sb + boB + LDSOFF(wn + sn * 16 + lr, ch));
      #pragma unroll
      for (int sm = 0; sm < 4; ++sm)
        #pragma unroll
        for (int sn = 0; sn < 2; ++sn)
          acc[sm][sn] = MFMA(a[sm], bb[sn], acc[sm][sn]);
    }
  }

  #pragma unroll
  for (int sm = 0; sm < 4; ++sm)
    #pragma unroll
    for (int sn = 0; sn < 2; ++sn) {
      const int col = n0 + wn + sn * 16 + lr;
      #pragma unroll
      for (int r = 0; r < 4; ++r) {
        const int ent = mt * 128 + wm + sm * 16 + qd * 4 + r;
        if (ent < cnt) {
          float v = acc[sm][sn][r];
          if (z == 0) {
            atomicAdd(out + (size_t)ent * DM + col, v);
          } else {
            const int   tok = list[(z - 1) * T_TOK + ent];
            const float g   = wgt [(z - 1) * T_TOK + ent];
            atomicAdd(out + (size_t)tok * DM + col, g * v);
          }
        }
      }
    }
}

// ---------------------------------------------------------------------------
extern "C" void kernel_launch(void* const* d_in, const int* in_sizes, int n_in,
                              void* d_out, int out_size, void* d_ws, size_t ws_size,
                              hipStream_t stream) {
  const float* x    = (const float*)d_in[0];
  const float* gw   = (const float*)d_in[1];
  const float* bias = (const float*)d_in[2];
  const float* sgu  = (const float*)d_in[3];
  const float* sdn  = (const float*)d_in[4];
  const float* egu  = (const float*)d_in[5];
  const float* edn  = (const float*)d_in[6];
  float* out = (float*)d_out;

  // workspace layout (bytes)
  char* ws = (char*)d_ws;
  int*            counts = (int*)(ws + 0);        // 16 ints
  int*            list   = (int*)(ws + 64);       // 16*2048 ints
  float*          wgt    = (float*)(ws + 131136); // 16*2048 floats
  unsigned short* Hall   = (unsigned short*)(ws + 262208); // 8192*512 bf16
  unsigned short* xb     = (unsigned short*)(ws + 8650816);
  unsigned short* sgub   = (unsigned short*)(ws + 10747968);
  unsigned short* sdnb   = (unsigned short*)(ws + 11796544);
  unsigned short* egub   = (unsigned short*)(ws + 12320832);
  unsigned short* ednb   = (unsigned short*)(ws + 29098048);
  const size_t need = 37486656;
  if (ws_size < need) return;

  hipMemsetAsync(counts, 0, 64, stream);
  prep_kernel<<<512 + 7040, 256, 0, stream>>>(
      x, gw, bias, counts, list, wgt, sgu, sdn, egu, edn,
      xb, sgub, sdnb, egub, ednb, out);
  gemm1_fused<<<dim3(8, 16, NE + 1), 256, 0, stream>>>(xb, sgub, egub, Hall, counts, list);
  gemm2_fused<<<dim3(8, 16, NE + 1), 256, 0, stream>>>(Hall, sdnb, ednb, out, counts, list, wgt);
}